// Round 6
// baseline (183.784 us; speedup 1.0000x reference)
//
#include <hip/hip_runtime.h>
#include <hip/hip_bf16.h>
#include <cstdint>

// Problem constants (MSA: B=8, N=1024, E=768, H=12, D=64)
#define BATCH 8
#define SEQ   1024
#define EMB   768
#define HEADS 12
#define HDIM  64
#define C3    2304          // 3*EMB
#define MROWS (BATCH*SEQ)   // 8192

typedef __attribute__((ext_vector_type(8)))  short bf16x8;
typedef __attribute__((ext_vector_type(4)))  short bf16x4;
typedef __attribute__((ext_vector_type(4)))  float f32x4;
typedef __attribute__((ext_vector_type(16))) float f32x16;

// fp32 -> bf16 round-to-nearest-even
static __device__ inline short f2bf(float f) {
    union { float f; uint32_t u; } v; v.f = f;
    uint32_t u = v.u + 0x7fff + ((v.u >> 16) & 1);
    return (short)(u >> 16);
}

// async global->LDS, 16B per lane. LDS dest = wave-uniform base + lane*16.
static __device__ inline void gload_lds16(const short* g, short* l) {
    __builtin_amdgcn_global_load_lds(
        (const __attribute__((address_space(1))) void*)g,
        (__attribute__((address_space(3))) void*)l, 16, 0, 0);
}

// ---------------------------------------------------------------------------
// Kernel 0: fp32 -> bf16 elementwise convert (8 elems/thread)
// ---------------------------------------------------------------------------
__global__ __launch_bounds__(256) void f32_to_bf16(const float* __restrict__ in,
                                                   short* __restrict__ out, int n8) {
    int i = blockIdx.x * 256 + threadIdx.x;
    if (i >= n8) return;
    float4 v0 = ((const float4*)in)[i * 2];
    float4 v1 = ((const float4*)in)[i * 2 + 1];
    bf16x8 o = { f2bf(v0.x), f2bf(v0.y), f2bf(v0.z), f2bf(v0.w),
                 f2bf(v1.x), f2bf(v1.y), f2bf(v1.z), f2bf(v1.w) };
    ((bf16x8*)out)[i] = o;
}

// ---------------------------------------------------------------------------
// Kernel 1 (RESTRUCTURED): bf16 MFMA GEMM with 32x32x16 MFMA, chunked LDS,
// double-buffered staging with prefetch-before-compute (1 barrier/iter).
//
// 128x128 tile, BK=32, 256 threads = 4 waves, wave = 64x64 quadrant as a
// 2x2 grid of 32x32 MFMA tiles, 2 chained k-steps (K=16 each) per iter.
//
// LDS layout: chunk = 16 rows x 32 bf16 (1024 B, one global_load_lds wave op)
// + 32 B pad -> 528 shorts. Chunk skew makes 32-row frag reads perfectly
// 8-phase (bank = 16(r&1) + 8(chunk&3...) distributes 8 lanes/4-bank group).
//
// A/B frag (32x32x16): lane holds row = lane&31, k = (lane>>5)*8 + j.
// C/D (m74/m101-verified): col = lane&31, row = (reg&3)+8*(reg>>2)+4*(lane>>5).
// ---------------------------------------------------------------------------
#define CHK 528   // chunk stride in shorts (16*32 + 16 pad shorts = 1056 B)

__global__ __launch_bounds__(256) void qkv_gemm_mfma(const short* __restrict__ xb,
                                                     const short* __restrict__ Wb,
                                                     const float* __restrict__ bias,
                                                     short* __restrict__ qkvb) {
    __shared__ short As[2][8 * CHK];   // 2 buffers x 8 chunks
    __shared__ short Bs[2][8 * CHK];

    const int bx = blockIdx.x;           // 18 N-tiles
    const int by = blockIdx.y;           // 64 M-tiles
    const int t = threadIdx.x;
    const int w = t >> 6;
    const int lane = t & 63;
    const int m0 = by * 128, n0 = bx * 128;
    const int wm = (w & 1) * 64, wn = (w >> 1) * 64;

    // ---- staging: wave w fills chunks w and 4+w of A and B ----
    const int srow = lane >> 2;          // 0..15
    const int scol = (lane & 3) * 8;     // 0,8,16,24
    const short* ga0 = xb + (size_t)(m0 + w * 16 + srow) * EMB + scol;
    const short* ga1 = xb + (size_t)(m0 + 64 + w * 16 + srow) * EMB + scol;
    const short* gb0 = Wb + (size_t)(n0 + w * 16 + srow) * EMB + scol;
    const short* gb1 = Wb + (size_t)(n0 + 64 + w * 16 + srow) * EMB + scol;

    // ---- frag-read offsets (shorts) ----
    const int l5  = lane >> 5;           // 0/1
    const int r31 = lane & 31;           // frag row within 32
    const int rlo = lane & 15;           // row within chunk
    const int rhi = (lane >> 4) & 1;     // chunk parity within 32 rows
    // A tile mt rows = wm + mt*32 + r31 -> chunk (wm>>4) + 2mt + rhi
    int aoff[2], boff[2];
    #pragma unroll
    for (int mt = 0; mt < 2; ++mt)
        aoff[mt] = ((wm >> 4) + 2 * mt + rhi) * CHK + rlo * 32 + l5 * 8;
    #pragma unroll
    for (int nt = 0; nt < 2; ++nt)
        boff[nt] = ((wn >> 4) + 2 * nt + rhi) * CHK + rlo * 32 + l5 * 8;

    f32x16 acc[2][2] = {};

    // ---- prologue: stage tile 0 into buffer 0 ----
    gload_lds16(ga0, &As[0][w * CHK]);
    gload_lds16(ga1, &As[0][(4 + w) * CHK]);
    gload_lds16(gb0, &Bs[0][w * CHK]);
    gload_lds16(gb1, &Bs[0][(4 + w) * CHK]);
    __syncthreads();

    for (int kt = 0; kt < 24; ++kt) {
        const int cur = kt & 1, nxt = cur ^ 1;
        if (kt < 23) {                    // prefetch tile kt+1 (async)
            const int ko = (kt + 1) * 32;
            gload_lds16(ga0 + ko, &As[nxt][w * CHK]);
            gload_lds16(ga1 + ko, &As[nxt][(4 + w) * CHK]);
            gload_lds16(gb0 + ko, &Bs[nxt][w * CHK]);
            gload_lds16(gb1 + ko, &Bs[nxt][(4 + w) * CHK]);
        }
        bf16x8 a[2][2], b[2][2];
        #pragma unroll
        for (int mt = 0; mt < 2; ++mt)
            #pragma unroll
            for (int s = 0; s < 2; ++s)
                a[mt][s] = *(bf16x8*)&As[cur][aoff[mt] + s * 16];
        #pragma unroll
        for (int nt = 0; nt < 2; ++nt)
            #pragma unroll
            for (int s = 0; s < 2; ++s)
                b[nt][s] = *(bf16x8*)&Bs[cur][boff[nt] + s * 16];
        #pragma unroll
        for (int mt = 0; mt < 2; ++mt)
            #pragma unroll
            for (int nt = 0; nt < 2; ++nt)
                #pragma unroll
                for (int s = 0; s < 2; ++s)
                    acc[mt][nt] = __builtin_amdgcn_mfma_f32_32x32x16_bf16(
                        a[mt][s], b[nt][s], acc[mt][nt], 0, 0, 0);
        __syncthreads();   // frag reads done (buf reuse) + prefetch drained
    }

    // ---- epilogue: bias + Q-channel scale (exact pow2), round to bf16 ----
    float bsv[2], scl[2];
    #pragma unroll
    for (int nt = 0; nt < 2; ++nt) {
        int n = n0 + wn + nt * 32 + r31;
        bsv[nt] = bias[n];
        scl[nt] = ((n % 192) < 64) ? 0.125f : 1.0f;
    }
    #pragma unroll
    for (int mt = 0; mt < 2; ++mt)
        #pragma unroll
        for (int nt = 0; nt < 2; ++nt) {
            int n = n0 + wn + nt * 32 + r31;
            #pragma unroll
            for (int reg = 0; reg < 16; ++reg) {
                int row = (reg & 3) + 8 * (reg >> 2) + 4 * l5;
                int m = m0 + wm + mt * 32 + row;
                float v = (acc[mt][nt][reg] + bsv[nt]) * scl[nt];
                qkvb[(size_t)m * C3 + n] = f2bf(v);
            }
        }
}

// ---------------------------------------------------------------------------
// Kernel 1b (round-4 verified, unchanged): V transpose to vt[(bh)*64+d][j].
// ---------------------------------------------------------------------------
__global__ __launch_bounds__(256) void v_transpose(const short* __restrict__ qkvb,
                                                   short* __restrict__ vt) {
    __shared__ int Lt[64][65];

    const int bh = blockIdx.x;
    const int jt = blockIdx.y;
    const int b = bh / HEADS, h = bh % HEADS;
    const int t = threadIdx.x;
    const int j0 = jt * 64;
    const size_t base = (size_t)b * SEQ * C3 + (size_t)h * 192 + 128;

    #pragma unroll
    for (int p = 0; p < 2; ++p) {
        int idx = p * 256 + t;
        int j = idx >> 3, d0 = (idx & 7) * 8;
        bf16x8 v = *(const bf16x8*)(qkvb + base + (size_t)(j0 + j) * C3 + d0);
        #pragma unroll
        for (int u = 0; u < 8; ++u)
            Lt[d0 + u][j] = (int)(unsigned short)v[u];
    }
    __syncthreads();
    #pragma unroll
    for (int p = 0; p < 2; ++p) {
        int idx = p * 256 + t;
        int d = idx >> 3, c8 = (idx & 7) * 8;
        bf16x8 o;
        #pragma unroll
        for (int u = 0; u < 8; ++u)
            o[u] = (short)Lt[d][c8 + u];
        *(bf16x8*)(vt + ((size_t)bh * 64 + d) * SEQ + j0 + c8) = o;
    }
}

// ---------------------------------------------------------------------------
// Kernel 2 (round-5 verified, unchanged): S^T-orientation flash attention,
// no-max softmax, packed b64 P-writes.
// ---------------------------------------------------------------------------
#define LDP 72   // LDS row stride in bf16 elems: 64 + 8 pad

__global__ __launch_bounds__(256, 4) void attn_mfma(const short* __restrict__ qkvb,
                                                    const short* __restrict__ vt,
                                                    float* __restrict__ out) {
    __shared__ short Ks[64][LDP];
    __shared__ short Vt[64][LDP];   // Vt[d][j]
    __shared__ short Ps[64][LDP];   // Q staging (prologue), then P strips

    const int bx   = blockIdx.x;
    const int qt   = bx & 15;
    const int h    = (bx >> 4) % HEADS;
    const int b    = bx / (16 * HEADS);
    const int t    = threadIdx.x;
    const int w    = t >> 6;
    const int lane = t & 63;
    const int c    = lane & 15;
    const int q    = lane >> 4;
    const int i0   = qt * 64;

    const size_t base = (size_t)b * SEQ * C3 + (size_t)h * 192;
    const short* vtb = vt + (size_t)(b * HEADS + h) * 64 * SEQ;

    // ---- stage Q tile (pre-scaled by 1/8) into Ps, grab B-frags ----
    #pragma unroll
    for (int p = 0; p < 2; ++p) {
        int idx = p * 256 + t;
        int i = idx >> 3, d0 = (idx & 7) << 3;
        *(bf16x8*)&Ps[i][d0] =
            *(const bf16x8*)(qkvb + base + (size_t)(i0 + i) * C3 + d0);
    }
    __syncthreads();
    const bf16x8 aq0 = *(bf16x8*)&Ps[w * 16 + c][q * 8];
    const bf16x8 aq1 = *(bf16x8*)&Ps[w * 16 + c][32 + q * 8];

    f32x4 o[4] = {{0.f,0.f,0.f,0.f},{0.f,0.f,0.f,0.f},
                  {0.f,0.f,0.f,0.f},{0.f,0.f,0.f,0.f}};
    float l_acc = 0.f;     // partial softmax denominator for query i=c

    for (int kt = 0; kt < 16; ++kt) {
        const int j0 = kt * 64;
        __syncthreads();
        // ---- stage K tile: Ks[j][d] ----
        #pragma unroll
        for (int p = 0; p < 2; ++p) {
            int idx = p * 256 + t;
            int j = idx >> 3, d0 = (idx & 7) << 3;
            *(bf16x8*)&Ks[j][d0] =
                *(const bf16x8*)(qkvb + base + 64 + (size_t)(j0 + j) * C3 + d0);
        }
        // ---- stage V^T tile: Vt[d][jlocal] ----
        #pragma unroll
        for (int p = 0; p < 2; ++p) {
            int idx = p * 256 + t;
            int d = idx >> 3, j8 = (idx & 7) << 3;
            *(bf16x8*)&Vt[d][j8] =
                *(const bf16x8*)(vtb + (size_t)d * SEQ + j0 + j8);
        }
        __syncthreads();

        // ---- S^T = K Q^T ----
        f32x4 s[4];
        #pragma unroll
        for (int mt = 0; mt < 4; ++mt) {
            bf16x8 a0 = *(bf16x8*)&Ks[mt * 16 + c][q * 8];
            bf16x8 a1 = *(bf16x8*)&Ks[mt * 16 + c][32 + q * 8];
            f32x4 acc = {0.f, 0.f, 0.f, 0.f};
            acc = __builtin_amdgcn_mfma_f32_16x16x32_bf16(a0, aq0, acc, 0, 0, 0);
            acc = __builtin_amdgcn_mfma_f32_16x16x32_bf16(a1, aq1, acc, 0, 0, 0);
            s[mt] = acc;
        }

        // ---- exp (no max), accumulate l, pack P as b64 writes ----
        #pragma unroll
        for (int mt = 0; mt < 4; ++mt) {
            float p0 = __expf(s[mt][0]);
            float p1 = __expf(s[mt][1]);
            float p2 = __expf(s[mt][2]);
            float p3 = __expf(s[mt][3]);
            l_acc += (p0 + p1) + (p2 + p3);
            bf16x4 pw = { f2bf(p0), f2bf(p1), f2bf(p2), f2bf(p3) };
            *(bf16x4*)&Ps[w * 16 + c][mt * 16 + 4 * q] = pw;
        }

        // ---- O += P V ----
        bf16x8 ap0 = *(bf16x8*)&Ps[w * 16 + c][q * 8];
        bf16x8 ap1 = *(bf16x8*)&Ps[w * 16 + c][32 + q * 8];
        #pragma unroll
        for (int dt = 0; dt < 4; ++dt) {
            bf16x8 b0 = *(bf16x8*)&Vt[dt * 16 + c][q * 8];
            bf16x8 b1 = *(bf16x8*)&Vt[dt * 16 + c][32 + q * 8];
            o[dt] = __builtin_amdgcn_mfma_f32_16x16x32_bf16(ap0, b0, o[dt], 0, 0, 0);
            o[dt] = __builtin_amdgcn_mfma_f32_16x16x32_bf16(ap1, b1, o[dt], 0, 0, 0);
        }
    }

    // ---- final l reduction ----
    l_acc += __shfl_xor(l_acc, 16, 64);
    l_acc += __shfl_xor(l_acc, 32, 64);
    float linv[4];
    #pragma unroll
    for (int r = 0; r < 4; ++r)
        linv[r] = 1.0f / __shfl(l_acc, 4 * q + r, 64);

    // ---- epilogue ----
    #pragma unroll
    for (int dt = 0; dt < 4; ++dt)
        #pragma unroll
        for (int r = 0; r < 4; ++r) {
            int i = w * 16 + q * 4 + r;
            out[((size_t)b * SEQ + i0 + i) * EMB + h * HDIM + dt * 16 + c]
                = o[dt][r] * linv[r];
        }
}

// ---------------------------------------------------------------------------
extern "C" void kernel_launch(void* const* d_in, const int* in_sizes, int n_in,
                              void* d_out, int out_size, void* d_ws, size_t ws_size,
                              hipStream_t stream) {
    const float* x    = (const float*)d_in[0];   // (8,1024,768) fp32
    const float* W    = (const float*)d_in[1];   // (2304,768)   fp32
    const float* bias = (const float*)d_in[2];   // (2304,)      fp32
    float* out = (float*)d_out;

    short* xb   = (short*)d_ws;                       // 8192*768   bf16
    short* Wb   = xb + (size_t)MROWS * EMB;           // 2304*768   bf16
    short* qkvb = Wb + (size_t)C3 * EMB;              // 8192*2304  bf16
    short* vt   = qkvb + (size_t)MROWS * C3;          // 96*64*1024 bf16

    f32_to_bf16<<<(MROWS * EMB / 8 + 255) / 256, 256, 0, stream>>>(x, xb, MROWS * EMB / 8);
    f32_to_bf16<<<(C3 * EMB / 8 + 255) / 256, 256, 0, stream>>>(W, Wb, C3 * EMB / 8);

    dim3 g1(C3 / 128, MROWS / 128);              // 18 x 64
    qkv_gemm_mfma<<<g1, 256, 0, stream>>>(xb, Wb, bias, qkvb);

    dim3 g2(BATCH * HEADS, SEQ / 64);            // 96 x 16
    v_transpose<<<g2, 256, 0, stream>>>(qkvb, vt);

    attn_mfma<<<BATCH * HEADS * (SEQ / 64), 256, 0, stream>>>(qkvb, vt, out);
}

// Round 7
// 181.919 us; speedup vs baseline: 1.0102x; 1.0102x over previous
//
#include <hip/hip_runtime.h>
#include <hip/hip_bf16.h>
#include <cstdint>

// Problem constants (MSA: B=8, N=1024, E=768, H=12, D=64)
#define BATCH 8
#define SEQ   1024
#define EMB   768
#define HEADS 12
#define HDIM  64
#define C3    2304          // 3*EMB
#define MROWS (BATCH*SEQ)   // 8192
#define KSLC  (EMB / 16)    // 48 k-slices

typedef __attribute__((ext_vector_type(8)))  short bf16x8;
typedef __attribute__((ext_vector_type(4)))  short bf16x4;
typedef __attribute__((ext_vector_type(4)))  float f32x4;
typedef __attribute__((ext_vector_type(16))) float f32x16;

// fp32 -> bf16 round-to-nearest-even
static __device__ inline short f2bf(float f) {
    union { float f; uint32_t u; } v; v.f = f;
    uint32_t u = v.u + 0x7fff + ((v.u >> 16) & 1);
    return (short)(u >> 16);
}

// ---------------------------------------------------------------------------
// Kernel 0 (NEW): fp32 -> bf16 convert + pack into MFMA-fragment tile order.
// Chunk(tile, ks) = 512 shorts = 32 rows x 16 k-elems; element (r, e) at
// chunk*512 + r*16 + e. Thread tid <-> (tile,ks,r): writes 32 B contiguous;
// consecutive lanes contiguous (fully coalesced stores).
// ---------------------------------------------------------------------------
__global__ __launch_bounds__(256) void pack_bf16(const float* __restrict__ in,
                                                 short* __restrict__ out) {
    const int tid = blockIdx.x * 256 + threadIdx.x;   // (tile*48+ks)*32 + r
    const int r    = tid & 31;
    const int ks   = (tid >> 5) % KSLC;
    const int tile = tid / (KSLC * 32);
    const int row  = tile * 32 + r;

    const float* src = in + (size_t)row * EMB + ks * 16;
    float4 v0 = ((const float4*)src)[0];
    float4 v1 = ((const float4*)src)[1];
    float4 v2 = ((const float4*)src)[2];
    float4 v3 = ((const float4*)src)[3];
    bf16x8 o0 = { f2bf(v0.x), f2bf(v0.y), f2bf(v0.z), f2bf(v0.w),
                  f2bf(v1.x), f2bf(v1.y), f2bf(v1.z), f2bf(v1.w) };
    bf16x8 o1 = { f2bf(v2.x), f2bf(v2.y), f2bf(v2.z), f2bf(v2.w),
                  f2bf(v3.x), f2bf(v3.y), f2bf(v3.z), f2bf(v3.w) };
    short* dst = out + (size_t)tid * 16;
    *(bf16x8*)(dst)     = o0;
    *(bf16x8*)(dst + 8) = o1;
}

// ---------------------------------------------------------------------------
// Kernel 1 (RESTRUCTURED): LDS-free, barrier-free bf16 MFMA GEMM.
// 128x128 block tile, 4 waves, wave = 64x64 quadrant = 2x2 of 32x32 MFMA.
// A/B pre-packed in fragment order: every frag = one coalesced 1 KB
// global_load_dwordx4 per wave (addr += 1024 B per k-slice -> streaming).
// K-loop: 48 x {4 loads + 4 MFMA}, no __syncthreads at all.
// C/D layout (HW-verified round 6): col=lane&31, row=(reg&3)+8(reg>>2)+4*l5.
// ---------------------------------------------------------------------------
__global__ __launch_bounds__(256) void qkv_gemm_mfma(const short* __restrict__ xb2,
                                                     const short* __restrict__ Wb2,
                                                     const float* __restrict__ bias,
                                                     short* __restrict__ qkvb) {
    const int bx = blockIdx.x;           // 18 N-tiles
    const int by = blockIdx.y;           // 64 M-tiles
    const int t = threadIdx.x;
    const int w = t >> 6;
    const int lane = t & 63;
    const int l5  = lane >> 5;
    const int r31 = lane & 31;
    const int m0 = by * 128, n0 = bx * 128;
    const int wm = (w & 1) * 64, wn = (w >> 1) * 64;

    const int laneoff = r31 * 16 + l5 * 8;
    const short* pa0 = xb2 + ((size_t)((m0 + wm) >> 5) * KSLC) * 512 + laneoff;
    const short* pa1 = pa0 + (size_t)KSLC * 512;
    const short* pb0 = Wb2 + ((size_t)((n0 + wn) >> 5) * KSLC) * 512 + laneoff;
    const short* pb1 = pb0 + (size_t)KSLC * 512;

    f32x16 acc[2][2] = {};

    #pragma unroll 4
    for (int ks = 0; ks < KSLC; ++ks) {
        bf16x8 a0 = *(const bf16x8*)(pa0 + ks * 512);
        bf16x8 a1 = *(const bf16x8*)(pa1 + ks * 512);
        bf16x8 b0 = *(const bf16x8*)(pb0 + ks * 512);
        bf16x8 b1 = *(const bf16x8*)(pb1 + ks * 512);
        acc[0][0] = __builtin_amdgcn_mfma_f32_32x32x16_bf16(a0, b0, acc[0][0], 0, 0, 0);
        acc[0][1] = __builtin_amdgcn_mfma_f32_32x32x16_bf16(a0, b1, acc[0][1], 0, 0, 0);
        acc[1][0] = __builtin_amdgcn_mfma_f32_32x32x16_bf16(a1, b0, acc[1][0], 0, 0, 0);
        acc[1][1] = __builtin_amdgcn_mfma_f32_32x32x16_bf16(a1, b1, acc[1][1], 0, 0, 0);
    }

    // ---- epilogue: bias + Q-channel scale (exact pow2), round to bf16 ----
    float bsv[2], scl[2];
    #pragma unroll
    for (int nt = 0; nt < 2; ++nt) {
        int n = n0 + wn + nt * 32 + r31;
        bsv[nt] = bias[n];
        scl[nt] = ((n % 192) < 64) ? 0.125f : 1.0f;
    }
    #pragma unroll
    for (int mt = 0; mt < 2; ++mt)
        #pragma unroll
        for (int nt = 0; nt < 2; ++nt) {
            int n = n0 + wn + nt * 32 + r31;
            #pragma unroll
            for (int reg = 0; reg < 16; ++reg) {
                int row = (reg & 3) + 8 * (reg >> 2) + 4 * l5;
                int m = m0 + wm + mt * 32 + row;
                float v = (acc[mt][nt][reg] + bsv[nt]) * scl[nt];
                qkvb[(size_t)m * C3 + n] = f2bf(v);
            }
        }
}

// ---------------------------------------------------------------------------
// Kernel 1b (round-4 verified, unchanged): V transpose to vt[(bh)*64+d][j].
// ---------------------------------------------------------------------------
__global__ __launch_bounds__(256) void v_transpose(const short* __restrict__ qkvb,
                                                   short* __restrict__ vt) {
    __shared__ int Lt[64][65];

    const int bh = blockIdx.x;
    const int jt = blockIdx.y;
    const int b = bh / HEADS, h = bh % HEADS;
    const int t = threadIdx.x;
    const int j0 = jt * 64;
    const size_t base = (size_t)b * SEQ * C3 + (size_t)h * 192 + 128;

    #pragma unroll
    for (int p = 0; p < 2; ++p) {
        int idx = p * 256 + t;
        int j = idx >> 3, d0 = (idx & 7) * 8;
        bf16x8 v = *(const bf16x8*)(qkvb + base + (size_t)(j0 + j) * C3 + d0);
        #pragma unroll
        for (int u = 0; u < 8; ++u)
            Lt[d0 + u][j] = (int)(unsigned short)v[u];
    }
    __syncthreads();
    #pragma unroll
    for (int p = 0; p < 2; ++p) {
        int idx = p * 256 + t;
        int d = idx >> 3, c8 = (idx & 7) * 8;
        bf16x8 o;
        #pragma unroll
        for (int u = 0; u < 8; ++u)
            o[u] = (short)Lt[d][c8 + u];
        *(bf16x8*)(vt + ((size_t)bh * 64 + d) * SEQ + j0 + c8) = o;
    }
}

// ---------------------------------------------------------------------------
// Kernel 2 (round-5 verified, unchanged): S^T-orientation flash attention,
// no-max softmax, packed b64 P-writes.
// ---------------------------------------------------------------------------
#define LDP 72   // LDS row stride in bf16 elems: 64 + 8 pad

__global__ __launch_bounds__(256, 4) void attn_mfma(const short* __restrict__ qkvb,
                                                    const short* __restrict__ vt,
                                                    float* __restrict__ out) {
    __shared__ short Ks[64][LDP];
    __shared__ short Vt[64][LDP];   // Vt[d][j]
    __shared__ short Ps[64][LDP];   // Q staging (prologue), then P strips

    const int bx   = blockIdx.x;
    const int qt   = bx & 15;
    const int h    = (bx >> 4) % HEADS;
    const int b    = bx / (16 * HEADS);
    const int t    = threadIdx.x;
    const int w    = t >> 6;
    const int lane = t & 63;
    const int c    = lane & 15;
    const int q    = lane >> 4;
    const int i0   = qt * 64;

    const size_t base = (size_t)b * SEQ * C3 + (size_t)h * 192;
    const short* vtb = vt + (size_t)(b * HEADS + h) * 64 * SEQ;

    // ---- stage Q tile (pre-scaled by 1/8) into Ps, grab B-frags ----
    #pragma unroll
    for (int p = 0; p < 2; ++p) {
        int idx = p * 256 + t;
        int i = idx >> 3, d0 = (idx & 7) << 3;
        *(bf16x8*)&Ps[i][d0] =
            *(const bf16x8*)(qkvb + base + (size_t)(i0 + i) * C3 + d0);
    }
    __syncthreads();
    const bf16x8 aq0 = *(bf16x8*)&Ps[w * 16 + c][q * 8];
    const bf16x8 aq1 = *(bf16x8*)&Ps[w * 16 + c][32 + q * 8];

    f32x4 o[4] = {{0.f,0.f,0.f,0.f},{0.f,0.f,0.f,0.f},
                  {0.f,0.f,0.f,0.f},{0.f,0.f,0.f,0.f}};
    float l_acc = 0.f;     // partial softmax denominator for query i=c

    for (int kt = 0; kt < 16; ++kt) {
        const int j0 = kt * 64;
        __syncthreads();
        // ---- stage K tile: Ks[j][d] ----
        #pragma unroll
        for (int p = 0; p < 2; ++p) {
            int idx = p * 256 + t;
            int j = idx >> 3, d0 = (idx & 7) << 3;
            *(bf16x8*)&Ks[j][d0] =
                *(const bf16x8*)(qkvb + base + 64 + (size_t)(j0 + j) * C3 + d0);
        }
        // ---- stage V^T tile: Vt[d][jlocal] ----
        #pragma unroll
        for (int p = 0; p < 2; ++p) {
            int idx = p * 256 + t;
            int d = idx >> 3, j8 = (idx & 7) << 3;
            *(bf16x8*)&Vt[d][j8] =
                *(const bf16x8*)(vtb + (size_t)d * SEQ + j0 + j8);
        }
        __syncthreads();

        // ---- S^T = K Q^T ----
        f32x4 s[4];
        #pragma unroll
        for (int mt = 0; mt < 4; ++mt) {
            bf16x8 a0 = *(bf16x8*)&Ks[mt * 16 + c][q * 8];
            bf16x8 a1 = *(bf16x8*)&Ks[mt * 16 + c][32 + q * 8];
            f32x4 acc = {0.f, 0.f, 0.f, 0.f};
            acc = __builtin_amdgcn_mfma_f32_16x16x32_bf16(a0, aq0, acc, 0, 0, 0);
            acc = __builtin_amdgcn_mfma_f32_16x16x32_bf16(a1, aq1, acc, 0, 0, 0);
            s[mt] = acc;
        }

        // ---- exp (no max), accumulate l, pack P as b64 writes ----
        #pragma unroll
        for (int mt = 0; mt < 4; ++mt) {
            float p0 = __expf(s[mt][0]);
            float p1 = __expf(s[mt][1]);
            float p2 = __expf(s[mt][2]);
            float p3 = __expf(s[mt][3]);
            l_acc += (p0 + p1) + (p2 + p3);
            bf16x4 pw = { f2bf(p0), f2bf(p1), f2bf(p2), f2bf(p3) };
            *(bf16x4*)&Ps[w * 16 + c][mt * 16 + 4 * q] = pw;
        }

        // ---- O += P V ----
        bf16x8 ap0 = *(bf16x8*)&Ps[w * 16 + c][q * 8];
        bf16x8 ap1 = *(bf16x8*)&Ps[w * 16 + c][32 + q * 8];
        #pragma unroll
        for (int dt = 0; dt < 4; ++dt) {
            bf16x8 b0 = *(bf16x8*)&Vt[dt * 16 + c][q * 8];
            bf16x8 b1 = *(bf16x8*)&Vt[dt * 16 + c][32 + q * 8];
            o[dt] = __builtin_amdgcn_mfma_f32_16x16x32_bf16(ap0, b0, o[dt], 0, 0, 0);
            o[dt] = __builtin_amdgcn_mfma_f32_16x16x32_bf16(ap1, b1, o[dt], 0, 0, 0);
        }
    }

    // ---- final l reduction ----
    l_acc += __shfl_xor(l_acc, 16, 64);
    l_acc += __shfl_xor(l_acc, 32, 64);
    float linv[4];
    #pragma unroll
    for (int r = 0; r < 4; ++r)
        linv[r] = 1.0f / __shfl(l_acc, 4 * q + r, 64);

    // ---- epilogue ----
    #pragma unroll
    for (int dt = 0; dt < 4; ++dt)
        #pragma unroll
        for (int r = 0; r < 4; ++r) {
            int i = w * 16 + q * 4 + r;
            out[((size_t)b * SEQ + i0 + i) * EMB + h * HDIM + dt * 16 + c]
                = o[dt][r] * linv[r];
        }
}

// ---------------------------------------------------------------------------
extern "C" void kernel_launch(void* const* d_in, const int* in_sizes, int n_in,
                              void* d_out, int out_size, void* d_ws, size_t ws_size,
                              hipStream_t stream) {
    const float* x    = (const float*)d_in[0];   // (8,1024,768) fp32
    const float* W    = (const float*)d_in[1];   // (2304,768)   fp32
    const float* bias = (const float*)d_in[2];   // (2304,)      fp32
    float* out = (float*)d_out;

    short* xb2  = (short*)d_ws;                       // 8192*768   bf16 (packed)
    short* Wb2  = xb2 + (size_t)MROWS * EMB;          // 2304*768   bf16 (packed)
    short* qkvb = Wb2 + (size_t)C3 * EMB;             // 8192*2304  bf16
    short* vt   = qkvb + (size_t)MROWS * C3;          // 96*64*1024 bf16

    pack_bf16<<<MROWS * KSLC / 256, 256, 0, stream>>>(x, xb2);   // 1536 blocks
    pack_bf16<<<C3 * KSLC / 256, 256, 0, stream>>>(W, Wb2);      // 432 blocks

    dim3 g1(C3 / 128, MROWS / 128);              // 18 x 64
    qkv_gemm_mfma<<<g1, 256, 0, stream>>>(xb2, Wb2, bias, qkvb);

    dim3 g2(BATCH * HEADS, SEQ / 64);            // 96 x 16
    v_transpose<<<g2, 256, 0, stream>>>(qkvb, vt);

    attn_mfma<<<BATCH * HEADS * (SEQ / 64), 256, 0, stream>>>(qkvb, vt, out);
}